// Round 5
// baseline (282.248 us; speedup 1.0000x reference)
//
#include <hip/hip_runtime.h>

#define HDIM 128
#define VOCAB 800
#define FB 16
#define TILE 1024
#define TILE_N 512

#define ACCB(a, h) { \
    a.x += __uint_as_float(h.x << 16); \
    a.y += __uint_as_float(h.x & 0xffff0000u); \
    a.z += __uint_as_float(h.y << 16); \
    a.w += __uint_as_float(h.y & 0xffff0000u); }

static __device__ __forceinline__ unsigned short f2bf(float f) {
    unsigned int u = __float_as_uint(f);
    return (unsigned short)((u + 0x7fffu + ((u >> 16) & 1u)) >> 16);
}

// ---------- fused: E2 = (emb @ W_f) @ W_s_bot (blocks 0..799), bfs = b_f @ W_s_bot + b_s (block 800)
__global__ void k_prep(const float* __restrict__ emb, const float* __restrict__ W_f,
                       const float* __restrict__ W_s, const float* __restrict__ b_f,
                       const float* __restrict__ b_s, float* __restrict__ E2,
                       float* __restrict__ bfs) {
    __shared__ float e[HDIM], t1[HDIM];
    int j = threadIdx.x;
    int v = blockIdx.x;
    if (v < VOCAB) {
        e[j] = emb[(size_t)v * HDIM + j];
        __syncthreads();
        float a = 0.f;
        for (int k = 0; k < HDIM; ++k)
            a = fmaf(e[k], W_f[k * HDIM + j], a);
        t1[j] = a;
        __syncthreads();
        float b = 0.f;
        for (int k = 0; k < HDIM; ++k)
            b = fmaf(t1[k], W_s[(HDIM + k) * HDIM + j], b);
        E2[(size_t)v * HDIM + j] = b;
    } else {
        e[j] = b_f[j];
        __syncthreads();
        float b = b_s[j];
        for (int k = 0; k < HDIM; ++k)
            b = fmaf(e[k], W_s[(HDIM + k) * HDIM + j], b);
        bfs[j] = b;
    }
}

// ---------- fused: x -> bf16 (blocks 0..12499) + edge degree counts (blocks 12500..12890)
__global__ void k_cvt(const float* __restrict__ x, unsigned short* __restrict__ xb,
                      const int* __restrict__ row, const int* __restrict__ col,
                      int* __restrict__ cntr, int* __restrict__ cntc) {
    int b = blockIdx.x, t = threadIdx.x;
    if (b < 12500) {
        size_t i = ((size_t)b * 256 + t) * 8;
        float4 v0 = *reinterpret_cast<const float4*>(x + i);
        float4 v1 = *reinterpret_cast<const float4*>(x + i + 4);
        uint4 o;
        o.x = (unsigned)f2bf(v0.x) | ((unsigned)f2bf(v0.y) << 16);
        o.y = (unsigned)f2bf(v0.z) | ((unsigned)f2bf(v0.w) << 16);
        o.z = (unsigned)f2bf(v1.x) | ((unsigned)f2bf(v1.y) << 16);
        o.w = (unsigned)f2bf(v1.z) | ((unsigned)f2bf(v1.w) << 16);
        *reinterpret_cast<uint4*>(xb + i) = o;
    } else {
        int i = (b - 12500) * 256 + t;  // over E/4 = 100000 int4s
        if (i < 100000) {
            int4 r4 = reinterpret_cast<const int4*>(row)[i];
            int4 c4 = reinterpret_cast<const int4*>(col)[i];
            atomicAdd(&cntr[r4.x], 1); atomicAdd(&cntr[r4.y], 1);
            atomicAdd(&cntr[r4.z], 1); atomicAdd(&cntr[r4.w], 1);
            atomicAdd(&cntc[c4.x], 1); atomicAdd(&cntc[c4.y], 1);
            atomicAdd(&cntc[c4.z], 1); atomicAdd(&cntc[c4.w], 1);
        }
    }
}

// ---------- per-256-block sums, col then row (fused)
__global__ void k_bsum2(const int* __restrict__ cntc, const int* __restrict__ cntr,
                        int* __restrict__ bsc, int* __restrict__ bsr, int NBC, int F, int N) {
    __shared__ int s[256];
    int t = threadIdx.x;
    const int* cnt;
    int* bsum;
    int bb, L;
    if ((int)blockIdx.x < NBC) { cnt = cntc; bsum = bsc; bb = blockIdx.x; L = F; }
    else                       { cnt = cntr; bsum = bsr; bb = blockIdx.x - NBC; L = N; }
    int i = bb * 256 + t;
    s[t] = (i < L) ? cnt[i] : 0;
    __syncthreads();
    for (int o = 128; o > 0; o >>= 1) {
        if (t < o) s[t] += s[t + o];
        __syncthreads();
    }
    if (t == 0) bsum[bb] = s[0];
}

// ---------- exclusive scan of both block-sum arrays (2 blocks)
__global__ void k_scan2(int* __restrict__ bsc, int* __restrict__ bsr, int nbc, int nbr) {
    __shared__ int s[1024];
    int* bsum = (blockIdx.x == 0) ? bsc : bsr;
    int nb    = (blockIdx.x == 0) ? nbc : nbr;
    int t = threadIdx.x;
    int v = (t < nb) ? bsum[t] : 0;
    s[t] = v;
    __syncthreads();
    for (int o = 1; o < 1024; o <<= 1) {
        int a = (t >= o) ? s[t - o] : 0;
        __syncthreads();
        s[t] += a;
        __syncthreads();
    }
    if (t < nb) bsum[t] = s[t] - v;
}

// ---------- base[i] = bsum[block] + in-block exclusive scan (col + row fused)
__global__ void k_base2(const int* __restrict__ cntc, const int* __restrict__ cntr,
                        const int* __restrict__ bsc, const int* __restrict__ bsr,
                        int* __restrict__ basec, int* __restrict__ baser,
                        int NBC, int F, int N) {
    __shared__ int s[256];
    int t = threadIdx.x;
    const int *cnt, *bsum;
    int* base;
    int bb, L;
    if ((int)blockIdx.x < NBC) { cnt = cntc; bsum = bsc; base = basec; bb = blockIdx.x; L = F; }
    else                       { cnt = cntr; bsum = bsr; base = baser; bb = blockIdx.x - NBC; L = N; }
    int i = bb * 256 + t;
    int v = (i < L) ? cnt[i] : 0;
    s[t] = v;
    __syncthreads();
    for (int o = 1; o < 256; o <<= 1) {
        int a = (t >= o) ? s[t - o] : 0;
        __syncthreads();
        s[t] += a;
        __syncthreads();
    }
    if (i < L) base[i] = bsum[bb] + s[t] - v;
}

// ---------- place edges into both CSRs (payload = opposite endpoint)
__global__ void k_place(const int* __restrict__ row, const int* __restrict__ col,
                        const int* __restrict__ basec, const int* __restrict__ baser,
                        int* __restrict__ curc, int* __restrict__ curr,
                        int* __restrict__ payc, int* __restrict__ payr, int E) {
    int e = blockIdx.x * 256 + threadIdx.x;
    if (e >= E) return;
    int r = row[e], c = col[e];
    int pc = atomicAdd(&curc[c], 1);
    payc[basec[c] + pc] = r;
    int pr = atomicAdd(&curr[r], 1);
    payr[baser[r] + pr] = c;
}

// ---------- fused per 16-fragment block: argmax(own fragment rows) + pool(xb bf16) + matvec
__global__ __launch_bounds__(256) void k_frag(
        const unsigned short* __restrict__ xb, const float* __restrict__ frags,
        const int* __restrict__ basec, const int* __restrict__ cntc,
        const int* __restrict__ payc, const float* __restrict__ W_s,
        const float* __restrict__ E2, const float* __restrict__ bfs,
        unsigned short* __restrict__ fembb) {
    __shared__ float s[FB][HDIM];
    __shared__ int eidx[TILE];
    __shared__ int fidv[FB];
    int t = threadIdx.x;
    int g = t >> 5, l = t & 31;
    int fb = blockIdx.x * FB;
    // Phase A: argmax over this block's 16 fragment rows (streaming, fills gather gaps)
#pragma unroll
    for (int rep = 0; rep < 2; ++rep) {
        int f = rep * 8 + g;
        const float4* r = reinterpret_cast<const float4*>(frags + (size_t)(fb + f) * VOCAB);
        float best = -1e30f;
        int bidx = 0;
        for (int i = l; i < VOCAB / 4; i += 32) {
            float4 v = r[i];
            int bI = i * 4;
            if (v.x > best) { best = v.x; bidx = bI + 0; }
            if (v.y > best) { best = v.y; bidx = bI + 1; }
            if (v.z > best) { best = v.z; bidx = bI + 2; }
            if (v.w > best) { best = v.w; bidx = bI + 3; }
        }
        for (int off = 16; off > 0; off >>= 1) {
            float ov = __shfl_xor(best, off, 32);
            int   oi = __shfl_xor(bidx, off, 32);
            if (ov > best || (ov == best && oi < bidx)) { best = ov; bidx = oi; }
        }
        if (l == 0) fidv[f] = bidx;
    }
    // Phase B: gather-mean from bf16 x (2 frags x 2-deep per 32-lane group)
    int fi0 = fb + g, fi1 = fb + 8 + g;
    int st0 = basec[fi0], d0 = cntc[fi0];
    int st1 = basec[fi1], d1 = cntc[fi1];
    int p0 = basec[fb];
    int pend = basec[fb + FB - 1] + cntc[fb + FB - 1];
    const uint2* x2 = reinterpret_cast<const uint2*>(xb);
    float4 a0A = make_float4(0.f, 0.f, 0.f, 0.f), a0B = a0A, a1A = a0A, a1B = a0A;
    for (int tb = p0; tb < pend; tb += TILE) {
        int nload = min(TILE, pend - tb);
        for (int i = t; i < nload; i += 256) eidx[i] = payc[tb + i];
        __syncthreads();
        int lim = tb + nload;
        int lo0 = max(st0, tb) - tb, hi0 = min(st0 + d0, lim) - tb;
        int lo1 = max(st1, tb) - tb, hi1 = min(st1 + d1, lim) - tb;
        int m = max(hi0 - lo0, hi1 - lo1);
        for (int j = 0; j < m; j += 2) {
            if (lo0 + j < hi0)     { uint2 h = x2[(size_t)eidx[lo0 + j]     * 32 + l]; ACCB(a0A, h); }
            if (lo0 + j + 1 < hi0) { uint2 h = x2[(size_t)eidx[lo0 + j + 1] * 32 + l]; ACCB(a0B, h); }
            if (lo1 + j < hi1)     { uint2 h = x2[(size_t)eidx[lo1 + j]     * 32 + l]; ACCB(a1A, h); }
            if (lo1 + j + 1 < hi1) { uint2 h = x2[(size_t)eidx[lo1 + j + 1] * 32 + l]; ACCB(a1B, h); }
        }
        __syncthreads();
    }
    float inv0 = 1.0f / fmaxf((float)d0, 1.0f);
    float inv1 = 1.0f / fmaxf((float)d1, 1.0f);
    float4 r0, r1;
    r0.x = (a0A.x + a0B.x) * inv0; r0.y = (a0A.y + a0B.y) * inv0;
    r0.z = (a0A.z + a0B.z) * inv0; r0.w = (a0A.w + a0B.w) * inv0;
    r1.x = (a1A.x + a1B.x) * inv1; r1.y = (a1A.y + a1B.y) * inv1;
    r1.z = (a1A.z + a1B.z) * inv1; r1.w = (a1A.w + a1B.w) * inv1;
    *reinterpret_cast<float4*>(&s[g][l * 4]) = r0;
    *reinterpret_cast<float4*>(&s[8 + g][l * 4]) = r1;
    __syncthreads();
    // Phase C: matvec, thread = dim d, 8 fragments per half-block
    int d = t & 127;
    int fh = t >> 7;
    float bv = bfs[d];
    float acc[8];
#pragma unroll
    for (int f = 0; f < 8; ++f)
        acc[f] = E2[(size_t)fidv[fh * 8 + f] * HDIM + d] + bv;
    for (int k = 0; k < HDIM; k += 4) {
        float w0 = W_s[(k + 0) * HDIM + d];
        float w1 = W_s[(k + 1) * HDIM + d];
        float w2 = W_s[(k + 2) * HDIM + d];
        float w3 = W_s[(k + 3) * HDIM + d];
#pragma unroll
        for (int f = 0; f < 8; ++f) {
            const float4 sv = *reinterpret_cast<const float4*>(&s[fh * 8 + f][k]);
            acc[f] = fmaf(sv.x, w0, acc[f]);
            acc[f] = fmaf(sv.y, w1, acc[f]);
            acc[f] = fmaf(sv.z, w2, acc[f]);
            acc[f] = fmaf(sv.w, w3, acc[f]);
        }
    }
#pragma unroll
    for (int f = 0; f < 8; ++f)
        fembb[(size_t)(fb + fh * 8 + f) * HDIM + d] = f2bf(acc[f]);
}

// ---------- node pool + divide; bf16 femb gather, 8 nodes x 1-deep per group
__global__ __launch_bounds__(256) void k_node(
        const unsigned short* __restrict__ fembb, const int* __restrict__ baser,
        const int* __restrict__ cntr, const int* __restrict__ payr,
        float* __restrict__ out, int N) {
    __shared__ int eidx[TILE_N];
    int t = threadIdx.x;
    int g = t >> 5, l = t & 31;
    int n0 = blockIdx.x * 64;
    int ng = n0 + g * 8;
    int p0 = baser[n0];
    int pend = baser[n0 + 63] + cntr[n0 + 63];
    const uint2* f2p = reinterpret_cast<const uint2*>(fembb);
    float4 a[8];
    int st_[8], dg_[8];
#pragma unroll
    for (int i = 0; i < 8; ++i) {
        st_[i] = baser[ng + i];
        dg_[i] = cntr[ng + i];
        a[i] = make_float4(0.f, 0.f, 0.f, 0.f);
    }
    for (int tb = p0; tb < pend; tb += TILE_N) {
        int nload = min(TILE_N, pend - tb);
        for (int i = t; i < nload; i += 256) eidx[i] = payr[tb + i];
        __syncthreads();
        int lim = tb + nload;
        int lo[8], hi[8];
        int m = 0;
#pragma unroll
        for (int i = 0; i < 8; ++i) {
            lo[i] = max(st_[i], tb) - tb;
            hi[i] = min(st_[i] + dg_[i], lim) - tb;
            m = max(m, hi[i] - lo[i]);
        }
        for (int j = 0; j < m; ++j) {
#pragma unroll
            for (int i = 0; i < 8; ++i) {
                if (lo[i] + j < hi[i]) {
                    uint2 h = f2p[(size_t)eidx[lo[i] + j] * 32 + l];
                    ACCB(a[i], h);
                }
            }
        }
        __syncthreads();
    }
    float4* o4 = reinterpret_cast<float4*>(out);
#pragma unroll
    for (int i = 0; i < 8; ++i) {
        float inv = 1.0f / fmaxf((float)dg_[i], 1.0f);
        float4 r;
        r.x = a[i].x * inv; r.y = a[i].y * inv;
        r.z = a[i].z * inv; r.w = a[i].w * inv;
        o4[(size_t)(ng + i) * 32 + l] = r;
    }
}

extern "C" void kernel_launch(void* const* d_in, const int* in_sizes, int n_in,
                              void* d_out, int out_size, void* d_ws, size_t ws_size,
                              hipStream_t stream) {
    const float* x         = (const float*)d_in[0];
    const float* fragments = (const float*)d_in[1];
    const float* emb_table = (const float*)d_in[2];
    const float* W_f       = (const float*)d_in[3];
    const float* b_f       = (const float*)d_in[4];
    const float* W_s       = (const float*)d_in[5];
    const float* b_s       = (const float*)d_in[6];
    const int*   row       = (const int*)d_in[7];
    const int*   col       = (const int*)d_in[8];
    float* out = (float*)d_out;

    const int N = 200000, F = 50000, E = 400000;
    const int NBC = (F + 255) / 256;   // 196
    const int NBR = (N + 255) / 256;   // 782

    // xb (bf16 x, 51.2 MB) lives in d_out: dead before k_node overwrites out entirely.
    unsigned short* xb = (unsigned short*)d_out;

    unsigned short* fembb = (unsigned short*)d_ws;     // F*128 bf16 = 12.8 MB
    int* cntc  = (int*)(fembb + (size_t)F * HDIM);     // F
    int* cntr  = cntc + F;                             // N
    int* curc  = cntr + N;                             // F
    int* curr  = curc + F;                             // N
    int* basec = curr + N;                             // F
    int* baser = basec + F;                            // N
    int* bsc   = baser + N;                            // 1024
    int* bsr   = bsc + 1024;                           // 1024
    int* payc  = bsr + 1024;                           // E
    int* payr  = payc + E;                             // E
    float* E2  = (float*)(payr + E);                   // VOCAB*128
    float* bfs = E2 + VOCAB * HDIM;                    // 128

    hipMemsetAsync(cntc, 0, (size_t)(2 * (F + N)) * sizeof(int), stream);

    k_prep<<<VOCAB + 1, HDIM, 0, stream>>>(emb_table, W_f, W_s, b_f, b_s, E2, bfs);
    k_cvt<<<12500 + 391, 256, 0, stream>>>(x, xb, row, col, cntr, cntc);
    k_bsum2<<<NBC + NBR, 256, 0, stream>>>(cntc, cntr, bsc, bsr, NBC, F, N);
    k_scan2<<<2, 1024, 0, stream>>>(bsc, bsr, NBC, NBR);
    k_base2<<<NBC + NBR, 256, 0, stream>>>(cntc, cntr, bsc, bsr, basec, baser, NBC, F, N);
    k_place<<<(E + 255) / 256, 256, 0, stream>>>(row, col, basec, baser, curc, curr,
                                                 payc, payr, E);
    k_frag<<<F / FB, 256, 0, stream>>>(xb, fragments, basec, cntc, payc, W_s, E2, bfs, fembb);
    k_node<<<N / 64, 256, 0, stream>>>(fembb, baser, cntr, payr, out, N);
}